// Round 8
// baseline (220.404 us; speedup 1.0000x reference)
//
#include <hip/hip_runtime.h>
#include <cstdint>
#include <cstddef>

#define B_   16
#define C_   512
#define H_   32
#define W_   32
#define HW_  1024
#define TC_  64
#define T_   48

typedef unsigned short u16;
typedef __attribute__((ext_vector_type(8))) short short8v;
typedef __attribute__((ext_vector_type(4))) float f32x4;

// ---------------------------------------------------------------------------
// bf16 helpers
// ---------------------------------------------------------------------------
__device__ __forceinline__ u16 tobf(float x) {
    unsigned u = __float_as_uint(x);
    return (u16)((u + 0x7FFFu + ((u >> 16) & 1u)) >> 16);    // RTNE
}
__device__ __forceinline__ float frombf(u16 h) {
    return __uint_as_float(((unsigned)h) << 16);
}

__device__ __forceinline__ void gld16(const void* g, void* l) {
    __builtin_amdgcn_global_load_lds(
        (const __attribute__((address_space(1))) void*)g,
        (__attribute__((address_space(3))) void*)l, 16, 0, 0);
}

// ---------------------------------------------------------------------------
// 1) Frobenius-norm helpers
// ---------------------------------------------------------------------------
__global__ void k_colsq(const float* __restrict__ x, float* __restrict__ partial) {
    int bid = blockIdx.x;
    int col = (bid & 3) * 256 + threadIdx.x;
    int r0  = (bid >> 2) * 256;
    const float* p = x + (size_t)r0 * HW_ + col;
    float s = 0.f;
    for (int r = 0; r < 256; ++r) { float v = p[(size_t)r * HW_]; s += v * v; }
    partial[(size_t)(bid >> 2) * HW_ + col] = s;
}

__global__ void k_rsqrt(const float* __restrict__ partial, float* __restrict__ ninv) {
    int i = blockIdx.x * 256 + threadIdx.x;
    if (i < HW_) {
        float s = 0.f;
        for (int r = 0; r < 32; ++r) s += partial[(size_t)r * HW_ + i];
        ninv[i] = rsqrtf(s);
    }
}

// ---------------------------------------------------------------------------
// 2) transpose + normalize: x [B,C,HW] -> xnH bf16 [B,HW,C]
// ---------------------------------------------------------------------------
__global__ void k_transpose(const float* __restrict__ x, const float* __restrict__ ninv,
                            u16* __restrict__ obH) {
    __shared__ float tile[32][33];
    int b  = blockIdx.z;
    int m0 = blockIdx.x * 32, c0 = blockIdx.y * 32;
    int tx = threadIdx.x, ty = threadIdx.y;
    const float* xb = x + (size_t)b * C_ * HW_;
    #pragma unroll
    for (int j = 0; j < 32; j += 8)
        tile[ty + j][tx] = xb[(size_t)(c0 + ty + j) * HW_ + m0 + tx];
    __syncthreads();
    size_t base = (size_t)b * HW_ * C_;
    #pragma unroll
    for (int j = 0; j < 32; j += 8) {
        int m = m0 + ty + j;
        obH[base + (size_t)m * C_ + c0 + tx] = tobf(tile[tx][ty + j] * ninv[m]);
    }
}

// ---------------------------------------------------------------------------
// 3) weight prep (hi plane only)
// ---------------------------------------------------------------------------
__global__ void k_packW(const float* __restrict__ in, u16* __restrict__ oh) {
    size_t i = (size_t)blockIdx.x * 256 + threadIdx.x;
    oh[i] = tobf(in[i]);
}
__global__ void k_packFG(const float* __restrict__ fW, const float* __restrict__ gW,
                         const float* __restrict__ fb, const float* __restrict__ gb,
                         u16* __restrict__ oh, float* __restrict__ fgb) {
    int idx = blockIdx.x * 256 + threadIdx.x;   // 65536
    int row = idx >> 9, c = idx & 511;
    float v = (row < 64) ? fW[row * 512 + c] : gW[(row - 64) * 512 + c];
    oh[idx] = tobf(v);
    if (idx < 128) fgb[idx] = (idx < 64) ? fb[idx] : gb[idx - 64];
}

// ---------------------------------------------------------------------------
// 4a) 1-term bf16 MFMA GEMM, 128x128 tile, 4 waves, KU-unrolled (r4/r6 proven
//     synchronous structure). Swizzle verified r3-r7.
//     EPI 0: Cf fp32 = acc
//     EPI 2: Ch = bf16(scale*acc + frombf(Ch))
//     EPI 4: Ch = bf16(acc)
//     EPI 5: Ch = bf16(acc + bias[row])
//     EPI 6: Ch = bf16(acc + bias[col])
// ---------------------------------------------------------------------------
template<int PERMB, int EPI, int KU>
__global__ __launch_bounds__(256) void k_gemm1(
    const u16* __restrict__ A, const u16* __restrict__ Bm,
    const float* __restrict__ bias,
    float* __restrict__ Cf, u16* __restrict__ Ch,
    const float* __restrict__ scaleP,
    int N, int K, int lda, int ldb, long sA, long sB, long sC)
{
    __shared__ u16 lds[8192 * KU];
    const int b = blockIdx.z;
    const u16* pA = A + (size_t)b * sA;
    const u16* pB = Bm + (size_t)b * sB;
    const int m0 = blockIdx.y * 128, n0 = blockIdx.x * 128;
    const int tid = threadIdx.x, wave = tid >> 6, lane = tid & 63;
    const int wm = wave >> 1, wn = wave & 1;
    const int g = lane >> 4;

    f32x4 acc[4][4];
    #pragma unroll
    for (int i = 0; i < 4; ++i)
        #pragma unroll
        for (int j = 0; j < 4; ++j) { f32x4 z = {0.f,0.f,0.f,0.f}; acc[i][j] = z; }

    for (int kt = 0; kt < (K >> 5); kt += KU) {
        __syncthreads();
        #pragma unroll
        for (int u = 0; u < KU; ++u) {
            const int k0 = (kt + u) << 5;
            u16* lb = lds + u * 8192;
            #pragma unroll
            for (int q = 0; q < 4; ++q) {
                int ci = wave * 4 + q;
                bool isA = ci < 8;
                int li = ci & 7;
                const u16* gp = isA ? pA : pB;
                int ld = isA ? lda : ldb;
                int rb = isA ? m0 : n0;
                int rp = li * 8 + (lane >> 3);
                int gg = (lane & 7) ^ (rp & 7);
                int r  = rp * 2 + (gg >> 2);
                int kc = k0 + (gg & 3) * 8;
                int rowg = rb + r;
                if (PERMB && !isA) rowg = ((rowg & 31) << 5) | (rowg >> 5);
                gld16(gp + (size_t)rowg * ld + kc,
                      lb + (isA ? 0 : 4096) + li * 512 + lane * 8);
            }
        }
        __syncthreads();
        #pragma unroll
        for (int u = 0; u < KU; ++u) {
            const u16* As = lds + u * 8192;
            const u16* Bs = As + 4096;
            short8v av[4];
            #pragma unroll
            for (int i = 0; i < 4; ++i) {
                int r = wm * 64 + i * 16 + (lane & 15);
                int rp = r >> 1, gg = ((r & 1) << 2) + g;
                av[i] = *(const short8v*)(As + rp * 64 + ((gg ^ (rp & 7)) << 3));
            }
            #pragma unroll
            for (int j = 0; j < 4; ++j) {
                int r = wn * 64 + j * 16 + (lane & 15);
                int rp = r >> 1, gg = ((r & 1) << 2) + g;
                short8v bv = *(const short8v*)(Bs + rp * 64 + ((gg ^ (rp & 7)) << 3));
                #pragma unroll
                for (int i = 0; i < 4; ++i)
                    acc[i][j] = __builtin_amdgcn_mfma_f32_16x16x32_bf16(av[i], bv, acc[i][j], 0, 0, 0);
            }
        }
    }

    const float sc = (EPI == 2) ? scaleP[0] : 0.f;
    const int colbase = n0 + wn * 64 + (lane & 15);
    const int rowbase = m0 + wm * 64 + ((lane >> 4) << 2);
    #pragma unroll
    for (int i = 0; i < 4; ++i)
        #pragma unroll
        for (int j = 0; j < 4; ++j) {
            int col = colbase + j * 16;
            #pragma unroll
            for (int rg = 0; rg < 4; ++rg) {
                int row = rowbase + i * 16 + rg;
                size_t idx = (size_t)b * sC + (size_t)row * N + col;
                float a = acc[i][j][rg];
                if (EPI == 0)      Cf[idx] = a;
                else if (EPI == 2) Ch[idx] = tobf(sc * a + frombf(Ch[idx]));
                else if (EPI == 4) Ch[idx] = tobf(a);
                else if (EPI == 5) Ch[idx] = tobf(a + bias[row]);
                else               Ch[idx] = tobf(a + bias[col]);
            }
        }
}

// ---------------------------------------------------------------------------
// 4b) 1-term bf16 MFMA GEMM, 128x256 tile, 8 waves, KU-unrolled.
// ---------------------------------------------------------------------------
template<int PERMB, int EPI, int KU>
__global__ __launch_bounds__(512) void k_gemm2(
    const u16* __restrict__ A, const u16* __restrict__ Bm,
    const float* __restrict__ bias,
    float* __restrict__ Cf, u16* __restrict__ Ch,
    const float* __restrict__ scaleP,
    int N, int K, int lda, int ldb, long sA, long sB, long sC)
{
    __shared__ u16 lds[12288 * KU];
    const int b = blockIdx.z;
    const u16* pA = A + (size_t)b * sA;
    const u16* pB = Bm + (size_t)b * sB;
    const int m0 = blockIdx.y * 128, n0 = blockIdx.x * 256;
    const int tid = threadIdx.x, wave = tid >> 6, lane = tid & 63;
    const int wm = wave >> 2, wn = wave & 3;
    const int g = lane >> 4;

    f32x4 acc[4][4];
    #pragma unroll
    for (int i = 0; i < 4; ++i)
        #pragma unroll
        for (int j = 0; j < 4; ++j) { f32x4 z = {0.f,0.f,0.f,0.f}; acc[i][j] = z; }

    for (int kt = 0; kt < (K >> 5); kt += KU) {
        __syncthreads();
        #pragma unroll
        for (int u = 0; u < KU; ++u) {
            const int k0 = (kt + u) << 5;
            u16* lb = lds + u * 12288;
            #pragma unroll
            for (int q = 0; q < 3; ++q) {
                int ci = wave * 3 + q;
                bool isA = ci < 8;
                int li = isA ? ci : ci - 8;
                const u16* gp = isA ? pA : pB;
                int ld = isA ? lda : ldb;
                int rb = isA ? m0 : n0;
                int rp = li * 8 + (lane >> 3);
                int gg = (lane & 7) ^ (rp & 7);
                int r  = rp * 2 + (gg >> 2);
                int kc = k0 + (gg & 3) * 8;
                int rowg = rb + r;
                if (PERMB && !isA) rowg = ((rowg & 31) << 5) | (rowg >> 5);
                gld16(gp + (size_t)rowg * ld + kc,
                      lb + (isA ? 0 : 4096) + li * 512 + lane * 8);
            }
        }
        __syncthreads();
        #pragma unroll
        for (int u = 0; u < KU; ++u) {
            const u16* As = lds + u * 12288;
            const u16* Bs = As + 4096;
            short8v av[4];
            #pragma unroll
            for (int i = 0; i < 4; ++i) {
                int r = wm * 64 + i * 16 + (lane & 15);
                int rp = r >> 1, gg = ((r & 1) << 2) + g;
                av[i] = *(const short8v*)(As + rp * 64 + ((gg ^ (rp & 7)) << 3));
            }
            #pragma unroll
            for (int j = 0; j < 4; ++j) {
                int r = wn * 64 + j * 16 + (lane & 15);
                int rp = r >> 1, gg = ((r & 1) << 2) + g;
                short8v bv = *(const short8v*)(Bs + rp * 64 + ((gg ^ (rp & 7)) << 3));
                #pragma unroll
                for (int i = 0; i < 4; ++i)
                    acc[i][j] = __builtin_amdgcn_mfma_f32_16x16x32_bf16(av[i], bv, acc[i][j], 0, 0, 0);
            }
        }
    }

    const float sc = (EPI == 2) ? scaleP[0] : 0.f;
    const int colbase = n0 + wn * 64 + (lane & 15);
    const int rowbase = m0 + wm * 64 + ((lane >> 4) << 2);
    #pragma unroll
    for (int i = 0; i < 4; ++i)
        #pragma unroll
        for (int j = 0; j < 4; ++j) {
            int col = colbase + j * 16;
            #pragma unroll
            for (int rg = 0; rg < 4; ++rg) {
                int row = rowbase + i * 16 + rg;
                size_t idx = (size_t)b * sC + (size_t)row * N + col;
                float a = acc[i][j][rg];
                if (EPI == 0)      Cf[idx] = a;
                else if (EPI == 2) Ch[idx] = tobf(sc * a + frombf(Ch[idx]));
                else if (EPI == 4) Ch[idx] = tobf(a);
                else if (EPI == 5) Ch[idx] = tobf(a + bias[row]);
                else               Ch[idx] = tobf(a + bias[col]);
            }
        }
}

// ---------------------------------------------------------------------------
// 5) row softmax on bf16 S, u16 in-place
// ---------------------------------------------------------------------------
__global__ __launch_bounds__(256) void k_softmax(u16* __restrict__ S) {
    size_t row = blockIdx.x;
    u16* r = S + row * (size_t)HW_;
    int t = threadIdx.x;
    ushort4 raw = ((const ushort4*)r)[t];
    float v0 = frombf(raw.x), v1 = frombf(raw.y), v2 = frombf(raw.z), v3 = frombf(raw.w);

    __shared__ float redm[4], reds[4];
    int wid = t >> 6, lane = t & 63;

    float m = fmaxf(fmaxf(v0, v1), fmaxf(v2, v3));
    for (int o = 32; o > 0; o >>= 1) m = fmaxf(m, __shfl_down(m, o));
    if (lane == 0) redm[wid] = m;
    __syncthreads();
    if (t == 0) redm[0] = fmaxf(fmaxf(redm[0], redm[1]), fmaxf(redm[2], redm[3]));
    __syncthreads();
    m = redm[0];

    v0 = expf(v0 - m); v1 = expf(v1 - m); v2 = expf(v2 - m); v3 = expf(v3 - m);
    float s = v0 + v1 + v2 + v3;
    for (int o = 32; o > 0; o >>= 1) s += __shfl_down(s, o);
    if (lane == 0) reds[wid] = s;
    __syncthreads();
    if (t == 0) reds[0] = reds[0] + reds[1] + reds[2] + reds[3];
    __syncthreads();
    float inv = 1.f / reds[0];
    ushort4 o4;
    o4.x = tobf(v0 * inv); o4.y = tobf(v1 * inv);
    o4.z = tobf(v2 * inv); o4.w = tobf(v3 * inv);
    ((ushort4*)r)[t] = o4;
}

// ---------------------------------------------------------------------------
// 6) single-plane u16 transpose of fdd flat view [512][1024] -> fddT [1024][512]
// ---------------------------------------------------------------------------
__global__ void k_tposeU1(const u16* __restrict__ src, u16* __restrict__ dst) {
    __shared__ u16 tile[32][33];
    int b = blockIdx.z;
    const u16* sb = src + (size_t)b * (C_ * HW_);
    u16* db = dst + (size_t)b * (C_ * HW_);
    int c0 = blockIdx.x * 32, r0 = blockIdx.y * 32;
    int tx = threadIdx.x, ty = threadIdx.y;
    #pragma unroll
    for (int j = 0; j < 32; j += 8)
        tile[ty + j][tx] = sb[(size_t)(r0 + ty + j) * HW_ + c0 + tx];
    __syncthreads();
    #pragma unroll
    for (int j = 0; j < 32; j += 8)
        db[(size_t)(c0 + ty + j) * C_ + r0 + tx] = tile[tx][ty + j];
}

// ---------------------------------------------------------------------------
// 7) top-48, one WAVE per row (4 rows/block, no barriers, no serial region):
//    lane-max of 16 elems -> sort64 -> tau = 48th group-max (valid prune) ->
//    shfl-scan compaction to per-wave LDS -> sorted top-48 via fast paths.
// ---------------------------------------------------------------------------
__device__ __forceinline__ float sort64_desc(float v, int lane) {
    #pragma unroll
    for (int k = 2; k <= 64; k <<= 1) {
        #pragma unroll
        for (int j = k >> 1; j > 0; j >>= 1) {
            float o = __shfl_xor(v, j);
            bool takeMax = (((lane & k) == 0) == ((lane & j) == 0));
            v = takeMax ? fmaxf(v, o) : fminf(v, o);
        }
    }
    return v;
}
__device__ __forceinline__ float bmerge64_desc(float a, float b, int lane) {
    float br = __shfl(b, 63 - lane);
    float c = fmaxf(a, br);
    #pragma unroll
    for (int j = 32; j > 0; j >>= 1) {
        float o = __shfl_xor(c, j);
        c = ((lane & j) == 0) ? fmaxf(c, o) : fminf(c, o);
    }
    return c;
}

__global__ __launch_bounds__(256) void k_topk(const float* __restrict__ corr,
                                              float* __restrict__ topv) {
    __shared__ float buf[4][1024];
    int wave = threadIdx.x >> 6, lane = threadIdx.x & 63;
    int row = blockIdx.x * 4 + wave;
    const float4* rp = (const float4*)(corr + (size_t)row * HW_);

    float4 e[4];
    #pragma unroll
    for (int q = 0; q < 4; ++q) e[q] = rp[lane * 4 + q];

    float gm = -INFINITY;
    #pragma unroll
    for (int q = 0; q < 4; ++q)
        gm = fmaxf(gm, fmaxf(fmaxf(e[q].x, e[q].y), fmaxf(e[q].z, e[q].w)));
    float sorted = sort64_desc(gm, lane);
    float tau = __shfl(sorted, T_ - 1);          // 48th largest group-max

    int c = 0;
    #pragma unroll
    for (int q = 0; q < 4; ++q)
        c += (e[q].x >= tau) + (e[q].y >= tau) + (e[q].z >= tau) + (e[q].w >= tau);
    int sc = c;
    #pragma unroll
    for (int o = 1; o < 64; o <<= 1) {
        int t2 = __shfl_up(sc, o);
        if (lane >= o) sc += t2;
    }
    int off = sc - c;
    int cnt = __shfl(sc, 63);                    // >= 48 guaranteed

    float* wb = buf[wave];
    #pragma unroll
    for (int q = 0; q < 4; ++q) {
        if (e[q].x >= tau) wb[off++] = e[q].x;
        if (e[q].y >= tau) wb[off++] = e[q].y;
        if (e[q].z >= tau) wb[off++] = e[q].z;
        if (e[q].w >= tau) wb[off++] = e[q].w;
    }

    float* orow = topv + (size_t)row * T_;
    if (cnt <= 64) {
        float a = (lane < cnt) ? wb[lane] : -INFINITY;
        a = sort64_desc(a, lane);
        if (lane < T_) orow[lane] = fmaxf(a, 0.f);
    } else if (cnt <= 128) {
        float a  = sort64_desc(wb[lane], lane);
        float b2 = sort64_desc((lane < cnt - 64) ? wb[64 + lane] : -INFINITY, lane);
        float m2 = bmerge64_desc(a, b2, lane);
        if (lane < T_) orow[lane] = fmaxf(m2, 0.f);
    } else {
        int P = 256; while (P < cnt) P <<= 1;    // rare (ties)
        for (int i = cnt + lane; i < P; i += 64) wb[i] = -INFINITY;
        for (int k = 2; k <= P; k <<= 1)
            for (int j = k >> 1; j > 0; j >>= 1)
                for (int t2 = lane; t2 < P; t2 += 64) {
                    int ixj = t2 ^ j;
                    if (ixj > t2) {
                        float a = wb[t2], b3 = wb[ixj];
                        bool desc = ((t2 & k) == 0);
                        if (desc ? (a < b3) : (a > b3)) { wb[t2] = b3; wb[ixj] = a; }
                    }
                }
        if (lane < T_) orow[lane] = fmaxf(wb[lane], 0.f);
    }
}

// ---------------------------------------------------------------------------
// 8) column norm over (B,H) and final transpose
// ---------------------------------------------------------------------------
__global__ void k_colss(const float* __restrict__ topv, float* __restrict__ colss) {
    int o = blockIdx.x;
    int w = o / T_, t = o % T_;
    int lane = threadIdx.x;
    float s = 0.f;
    for (int i = lane; i < 512; i += 64) {
        int b = i >> 5, h = i & 31;
        float v = topv[(size_t)((b << 10) + (h << 5) + w) * T_ + t];
        s += v * v;
    }
    for (int off = 32; off > 0; off >>= 1) s += __shfl_down(s, off);
    if (lane == 0) colss[o] = s;
}

__global__ void k_final(const float* __restrict__ topv, const float* __restrict__ colss,
                        float* __restrict__ out) {
    int idx = blockIdx.x * 256 + threadIdx.x;
    if (idx >= B_ * T_ * HW_) return;
    int w = idx & 31;
    int h = (idx >> 5) & 31;
    int t = (idx >> 10) % T_;
    int b = idx / (T_ * HW_);
    float v = topv[(size_t)((b << 10) + (h << 5) + w) * T_ + t];
    out[idx] = v * rsqrtf(colss[w * T_ + t]);
}

// ---------------------------------------------------------------------------
extern "C" void kernel_launch(void* const* d_in, const int* in_sizes, int n_in,
                              void* d_out, int out_size, void* d_ws, size_t ws_size,
                              hipStream_t stream) {
    const float* x     = (const float*)d_in[0];
    const float* fW    = (const float*)d_in[1];
    const float* fb    = (const float*)d_in[2];
    const float* gW    = (const float*)d_in[3];
    const float* gb    = (const float*)d_in[4];
    const float* hW    = (const float*)d_in[5];
    const float* hb    = (const float*)d_in[6];
    const float* scale = (const float*)d_in[7];
    float* out = (float*)d_out;

    char* wsb = (char*)d_ws;
    float* part = (float*)(wsb + 0);                 // 131072 B
    float* ninv = (float*)(wsb + 131072);            // 4096 B
    u16*   hWh  = (u16*)(wsb + 135168);              // 524288 B
    u16*   fgWh = (u16*)(wsb + 1183744);             // 131072 B
    float* fgb  = (float*)(wsb + 1445888);           // 512 B
    u16*   xnH  = (u16*)(wsb + 1446400);             // 16 MB (xn bf16 -> fdd bf16)
    u16*   fgH  = (u16*)(wsb + 35000832);            // 4 MB (f|g bf16; later topv)
    u16*   fgL  = (u16*)(wsb + 39195136);            // 4 MB (later colss)
    u16*   hvTH = (u16*)(wsb + 43389440);            // 16 MB (hv bf16 -> fddT)
    float* S    = (float*)(wsb + 76943872);          // 64 MB (S/P u16 -> corr fp32)
    float* topv = (float*)fgH;
    float* colss= (float*)fgL;
    u16*   Sp   = (u16*)S;

    const long sXn = 524288;    // [1024][512] elements per batch
    const long sFG = 131072;    // [1024][128]
    const long sS  = 1048576;   // [1024][1024]

    // 1) per-pixel Frobenius norm
    k_colsq<<<128, 256, 0, stream>>>(x, part);
    k_rsqrt<<<4, 256, 0, stream>>>(part, ninv);

    // 2) normalized channel-last bf16 (single plane)
    k_transpose<<<dim3(32, 16, 16), dim3(32, 8), 0, stream>>>(x, ninv, xnH);

    // 3) weight planes
    k_packW<<<1024, 256, 0, stream>>>(hW, hWh);
    k_packFG<<<256, 256, 0, stream>>>(fW, gW, fb, gb, fgWh, fgb);

    // 4) fg = bf16(xn @ [fW|gW]^T + bias[col])  [B,1024,128]
    k_gemm1<0, 6, 2><<<dim3(1, 8, 16), 256, 0, stream>>>(
        xnH, fgWh, fgb, nullptr, fgH, nullptr,
        128, 512, 512, 512, sXn, 0, sFG);

    // 5) hv = bf16(hW @ xn^T + hb[row])  [B,512,1024]
    k_gemm2<0, 5, 2><<<dim3(4, 4, 16), 512, 0, stream>>>(
        hWh, xnH, hb, nullptr, hvTH, nullptr,
        1024, 512, 512, 512, 0, sXn, sXn);

    // 6) S = bf16(f @ perm(g)^T)  (K=64, W-major keys)
    k_gemm2<1, 4, 2><<<dim3(4, 8, 16), 512, 0, stream>>>(
        fgH, fgH + 64, nullptr, nullptr, Sp, nullptr,
        1024, 64, 128, 128, sFG, sFG, sS);

    // 7) softmax rows, u16 in place -> P bf16
    k_softmax<<<B_ * HW_, 256, 0, stream>>>(Sp);

    // 8) fdd = bf16(scale*(P @ hv^T) + xn), in place over xnH (128x256 tile)
    k_gemm2<0, 2, 2><<<dim3(2, 8, 16), 512, 0, stream>>>(
        Sp, hvTH, nullptr, nullptr, xnH, scale,
        512, 1024, 1024, 1024, sS, sXn, sXn);

    // 9) fddT: transpose flat [512][1024] view of fddH -> hvTH [1024][512]
    k_tposeU1<<<dim3(32, 16, 16), dim3(32, 8), 0, stream>>>(xnH, hvTH);

    // 10) corr = fdd @ fddT^T -> fp32 into S
    k_gemm2<0, 0, 2><<<dim3(4, 8, 16), 512, 0, stream>>>(
        xnH, hvTH, nullptr, S, nullptr, nullptr,
        1024, 512, 512, 512, sXn, sXn, sS);

    // 11) top-48 desc + relu (wave-per-row)
    k_topk<<<B_ * HW_ / 4, 256, 0, stream>>>(S, topv);

    // 12) norm over (B,H) + output transpose
    k_colss<<<W_ * T_, 64, 0, stream>>>(topv, colss);
    k_final<<<(B_ * T_ * HW_ + 255) / 256, 256, 0, stream>>>(topv, colss, out);
}

// Round 9
// 213.804 us; speedup vs baseline: 1.0309x; 1.0309x over previous
//
#include <hip/hip_runtime.h>
#include <cstdint>
#include <cstddef>

#define B_   16
#define C_   512
#define H_   32
#define W_   32
#define HW_  1024
#define TC_  64
#define T_   48

typedef unsigned short u16;
typedef __attribute__((ext_vector_type(8))) short short8v;
typedef __attribute__((ext_vector_type(4))) float f32x4;

// ---------------------------------------------------------------------------
// bf16 helpers
// ---------------------------------------------------------------------------
__device__ __forceinline__ u16 tobf(float x) {
    unsigned u = __float_as_uint(x);
    return (u16)((u + 0x7FFFu + ((u >> 16) & 1u)) >> 16);    // RTNE
}
__device__ __forceinline__ float frombf(u16 h) {
    return __uint_as_float(((unsigned)h) << 16);
}

__device__ __forceinline__ void gld16(const void* g, void* l) {
    __builtin_amdgcn_global_load_lds(
        (const __attribute__((address_space(1))) void*)g,
        (__attribute__((address_space(3))) void*)l, 16, 0, 0);
}

// ---------------------------------------------------------------------------
// 1) Frobenius-norm helpers
// ---------------------------------------------------------------------------
__global__ void k_colsq(const float* __restrict__ x, float* __restrict__ partial) {
    int bid = blockIdx.x;
    int col = (bid & 3) * 256 + threadIdx.x;
    int r0  = (bid >> 2) * 256;
    const float* p = x + (size_t)r0 * HW_ + col;
    float s = 0.f;
    for (int r = 0; r < 256; ++r) { float v = p[(size_t)r * HW_]; s += v * v; }
    partial[(size_t)(bid >> 2) * HW_ + col] = s;
}

__global__ void k_rsqrt(const float* __restrict__ partial, float* __restrict__ ninv) {
    int i = blockIdx.x * 256 + threadIdx.x;
    if (i < HW_) {
        float s = 0.f;
        for (int r = 0; r < 32; ++r) s += partial[(size_t)r * HW_ + i];
        ninv[i] = rsqrtf(s);
    }
}

// ---------------------------------------------------------------------------
// 2) transpose + normalize: x [B,C,HW] -> xnH bf16 [B,HW,C]
// ---------------------------------------------------------------------------
__global__ void k_transpose(const float* __restrict__ x, const float* __restrict__ ninv,
                            u16* __restrict__ obH) {
    __shared__ float tile[32][33];
    int b  = blockIdx.z;
    int m0 = blockIdx.x * 32, c0 = blockIdx.y * 32;
    int tx = threadIdx.x, ty = threadIdx.y;
    const float* xb = x + (size_t)b * C_ * HW_;
    #pragma unroll
    for (int j = 0; j < 32; j += 8)
        tile[ty + j][tx] = xb[(size_t)(c0 + ty + j) * HW_ + m0 + tx];
    __syncthreads();
    size_t base = (size_t)b * HW_ * C_;
    #pragma unroll
    for (int j = 0; j < 32; j += 8) {
        int m = m0 + ty + j;
        obH[base + (size_t)m * C_ + c0 + tx] = tobf(tile[tx][ty + j] * ninv[m]);
    }
}

// ---------------------------------------------------------------------------
// 3) weight prep (hi plane only)
// ---------------------------------------------------------------------------
__global__ void k_packW(const float* __restrict__ in, u16* __restrict__ oh) {
    size_t i = (size_t)blockIdx.x * 256 + threadIdx.x;
    oh[i] = tobf(in[i]);
}
__global__ void k_packFG(const float* __restrict__ fW, const float* __restrict__ gW,
                         const float* __restrict__ fb, const float* __restrict__ gb,
                         u16* __restrict__ oh, float* __restrict__ fgb) {
    int idx = blockIdx.x * 256 + threadIdx.x;   // 65536
    int row = idx >> 9, c = idx & 511;
    float v = (row < 64) ? fW[row * 512 + c] : gW[(row - 64) * 512 + c];
    oh[idx] = tobf(v);
    if (idx < 128) fgb[idx] = (idx < 64) ? fb[idx] : gb[idx - 64];
}

// ---------------------------------------------------------------------------
// 4a) 1-term bf16 MFMA GEMM, 128x128 tile, 4 waves, 2-phase counted-vmcnt
//     pipeline (T3/T4): STAGE(kt+1 -> buf^1); vmcnt(4) [keep prefetch in
//     flight]; raw s_barrier; compute buf; s_barrier. NO __syncthreads in
//     the K-loop (its vmcnt(0) drain was the r5 regression).
//     Swizzle verified r3-r8.
//     EPI 0: Cf fp32 = acc
//     EPI 2: Ch = bf16(scale*acc + frombf(Ch))
//     EPI 4: Ch = bf16(acc)
//     EPI 5: Ch = bf16(acc + bias[row])
//     EPI 6: Ch = bf16(acc + bias[col])
// ---------------------------------------------------------------------------
template<int PERMB, int EPI>
__global__ __launch_bounds__(256) void k_gemm1(
    const u16* __restrict__ A, const u16* __restrict__ Bm,
    const float* __restrict__ bias,
    float* __restrict__ Cf, u16* __restrict__ Ch,
    const float* __restrict__ scaleP,
    int N, int K, int lda, int ldb, long sA, long sB, long sC)
{
    __shared__ u16 lds[2 * 8192];
    const int b = blockIdx.z;
    const u16* pA = A + (size_t)b * sA;
    const u16* pB = Bm + (size_t)b * sB;
    const int m0 = blockIdx.y * 128, n0 = blockIdx.x * 128;
    const int tid = threadIdx.x, wave = tid >> 6, lane = tid & 63;
    const int wm = wave >> 1, wn = wave & 1;
    const int g = lane >> 4;

    f32x4 acc[4][4];
    #pragma unroll
    for (int i = 0; i < 4; ++i)
        #pragma unroll
        for (int j = 0; j < 4; ++j) { f32x4 z = {0.f,0.f,0.f,0.f}; acc[i][j] = z; }

    auto STAGE = [&](int kt, int half) {
        const int k0 = kt << 5;
        u16* lb = lds + half * 8192;
        #pragma unroll
        for (int q = 0; q < 4; ++q) {
            int ci = wave * 4 + q;
            bool isA = ci < 8;
            int li = ci & 7;
            const u16* gp = isA ? pA : pB;
            int ld = isA ? lda : ldb;
            int rb = isA ? m0 : n0;
            int rp = li * 8 + (lane >> 3);
            int gg = (lane & 7) ^ (rp & 7);
            int r  = rp * 2 + (gg >> 2);
            int kc = k0 + (gg & 3) * 8;
            int rowg = rb + r;
            if (PERMB && !isA) rowg = ((rowg & 31) << 5) | (rowg >> 5);
            gld16(gp + (size_t)rowg * ld + kc,
                  lb + (isA ? 0 : 4096) + li * 512 + lane * 8);
        }
    };
    auto COMPUTE = [&](int half) {
        const u16* As = lds + half * 8192;
        const u16* Bs = As + 4096;
        short8v av[4];
        #pragma unroll
        for (int i = 0; i < 4; ++i) {
            int r = wm * 64 + i * 16 + (lane & 15);
            int rp = r >> 1, gg = ((r & 1) << 2) + g;
            av[i] = *(const short8v*)(As + rp * 64 + ((gg ^ (rp & 7)) << 3));
        }
        #pragma unroll
        for (int j = 0; j < 4; ++j) {
            int r = wn * 64 + j * 16 + (lane & 15);
            int rp = r >> 1, gg = ((r & 1) << 2) + g;
            short8v bv = *(const short8v*)(Bs + rp * 64 + ((gg ^ (rp & 7)) << 3));
            #pragma unroll
            for (int i = 0; i < 4; ++i)
                acc[i][j] = __builtin_amdgcn_mfma_f32_16x16x32_bf16(av[i], bv, acc[i][j], 0, 0, 0);
        }
    };

    const int nkt = K >> 5;
    STAGE(0, 0);
    int cur = 0;
    for (int kt = 0; kt < nkt; ++kt) {
        if (kt + 1 < nkt) {
            STAGE(kt + 1, cur ^ 1);
            asm volatile("s_waitcnt vmcnt(4)" ::: "memory");
        } else {
            asm volatile("s_waitcnt vmcnt(0)" ::: "memory");
        }
        __builtin_amdgcn_s_barrier();
        __builtin_amdgcn_sched_barrier(0);
        COMPUTE(cur);
        __builtin_amdgcn_sched_barrier(0);
        __builtin_amdgcn_s_barrier();
        cur ^= 1;
    }

    const float sc = (EPI == 2) ? scaleP[0] : 0.f;
    const int colbase = n0 + wn * 64 + (lane & 15);
    const int rowbase = m0 + wm * 64 + ((lane >> 4) << 2);
    #pragma unroll
    for (int i = 0; i < 4; ++i)
        #pragma unroll
        for (int j = 0; j < 4; ++j) {
            int col = colbase + j * 16;
            #pragma unroll
            for (int rg = 0; rg < 4; ++rg) {
                int row = rowbase + i * 16 + rg;
                size_t idx = (size_t)b * sC + (size_t)row * N + col;
                float a = acc[i][j][rg];
                if (EPI == 0)      Cf[idx] = a;
                else if (EPI == 2) Ch[idx] = tobf(sc * a + frombf(Ch[idx]));
                else if (EPI == 4) Ch[idx] = tobf(a);
                else if (EPI == 5) Ch[idx] = tobf(a + bias[row]);
                else               Ch[idx] = tobf(a + bias[col]);
            }
        }
}

// ---------------------------------------------------------------------------
// 4b) 1-term bf16 MFMA GEMM, 128x256 tile, 8 waves, same 2-phase counted-vmcnt
//     pipeline (3 chunks/wave -> vmcnt(3)).
// ---------------------------------------------------------------------------
template<int PERMB, int EPI>
__global__ __launch_bounds__(512) void k_gemm2(
    const u16* __restrict__ A, const u16* __restrict__ Bm,
    const float* __restrict__ bias,
    float* __restrict__ Cf, u16* __restrict__ Ch,
    const float* __restrict__ scaleP,
    int N, int K, int lda, int ldb, long sA, long sB, long sC)
{
    __shared__ u16 lds[2 * 12288];
    const int b = blockIdx.z;
    const u16* pA = A + (size_t)b * sA;
    const u16* pB = Bm + (size_t)b * sB;
    const int m0 = blockIdx.y * 128, n0 = blockIdx.x * 256;
    const int tid = threadIdx.x, wave = tid >> 6, lane = tid & 63;
    const int wm = wave >> 2, wn = wave & 3;
    const int g = lane >> 4;

    f32x4 acc[4][4];
    #pragma unroll
    for (int i = 0; i < 4; ++i)
        #pragma unroll
        for (int j = 0; j < 4; ++j) { f32x4 z = {0.f,0.f,0.f,0.f}; acc[i][j] = z; }

    auto STAGE = [&](int kt, int half) {
        const int k0 = kt << 5;
        u16* lb = lds + half * 12288;
        #pragma unroll
        for (int q = 0; q < 3; ++q) {
            int ci = wave * 3 + q;
            bool isA = ci < 8;
            int li = isA ? ci : ci - 8;
            const u16* gp = isA ? pA : pB;
            int ld = isA ? lda : ldb;
            int rb = isA ? m0 : n0;
            int rp = li * 8 + (lane >> 3);
            int gg = (lane & 7) ^ (rp & 7);
            int r  = rp * 2 + (gg >> 2);
            int kc = k0 + (gg & 3) * 8;
            int rowg = rb + r;
            if (PERMB && !isA) rowg = ((rowg & 31) << 5) | (rowg >> 5);
            gld16(gp + (size_t)rowg * ld + kc,
                  lb + (isA ? 0 : 4096) + li * 512 + lane * 8);
        }
    };
    auto COMPUTE = [&](int half) {
        const u16* As = lds + half * 12288;
        const u16* Bs = As + 4096;
        short8v av[4];
        #pragma unroll
        for (int i = 0; i < 4; ++i) {
            int r = wm * 64 + i * 16 + (lane & 15);
            int rp = r >> 1, gg = ((r & 1) << 2) + g;
            av[i] = *(const short8v*)(As + rp * 64 + ((gg ^ (rp & 7)) << 3));
        }
        #pragma unroll
        for (int j = 0; j < 4; ++j) {
            int r = wn * 64 + j * 16 + (lane & 15);
            int rp = r >> 1, gg = ((r & 1) << 2) + g;
            short8v bv = *(const short8v*)(Bs + rp * 64 + ((gg ^ (rp & 7)) << 3));
            #pragma unroll
            for (int i = 0; i < 4; ++i)
                acc[i][j] = __builtin_amdgcn_mfma_f32_16x16x32_bf16(av[i], bv, acc[i][j], 0, 0, 0);
        }
    };

    const int nkt = K >> 5;
    STAGE(0, 0);
    int cur = 0;
    for (int kt = 0; kt < nkt; ++kt) {
        if (kt + 1 < nkt) {
            STAGE(kt + 1, cur ^ 1);
            asm volatile("s_waitcnt vmcnt(3)" ::: "memory");
        } else {
            asm volatile("s_waitcnt vmcnt(0)" ::: "memory");
        }
        __builtin_amdgcn_s_barrier();
        __builtin_amdgcn_sched_barrier(0);
        COMPUTE(cur);
        __builtin_amdgcn_sched_barrier(0);
        __builtin_amdgcn_s_barrier();
        cur ^= 1;
    }

    const float sc = (EPI == 2) ? scaleP[0] : 0.f;
    const int colbase = n0 + wn * 64 + (lane & 15);
    const int rowbase = m0 + wm * 64 + ((lane >> 4) << 2);
    #pragma unroll
    for (int i = 0; i < 4; ++i)
        #pragma unroll
        for (int j = 0; j < 4; ++j) {
            int col = colbase + j * 16;
            #pragma unroll
            for (int rg = 0; rg < 4; ++rg) {
                int row = rowbase + i * 16 + rg;
                size_t idx = (size_t)b * sC + (size_t)row * N + col;
                float a = acc[i][j][rg];
                if (EPI == 0)      Cf[idx] = a;
                else if (EPI == 2) Ch[idx] = tobf(sc * a + frombf(Ch[idx]));
                else if (EPI == 4) Ch[idx] = tobf(a);
                else if (EPI == 5) Ch[idx] = tobf(a + bias[row]);
                else               Ch[idx] = tobf(a + bias[col]);
            }
        }
}

// ---------------------------------------------------------------------------
// 5) row softmax on bf16 S, u16 in-place
// ---------------------------------------------------------------------------
__global__ __launch_bounds__(256) void k_softmax(u16* __restrict__ S) {
    size_t row = blockIdx.x;
    u16* r = S + row * (size_t)HW_;
    int t = threadIdx.x;
    ushort4 raw = ((const ushort4*)r)[t];
    float v0 = frombf(raw.x), v1 = frombf(raw.y), v2 = frombf(raw.z), v3 = frombf(raw.w);

    __shared__ float redm[4], reds[4];
    int wid = t >> 6, lane = t & 63;

    float m = fmaxf(fmaxf(v0, v1), fmaxf(v2, v3));
    for (int o = 32; o > 0; o >>= 1) m = fmaxf(m, __shfl_down(m, o));
    if (lane == 0) redm[wid] = m;
    __syncthreads();
    if (t == 0) redm[0] = fmaxf(fmaxf(redm[0], redm[1]), fmaxf(redm[2], redm[3]));
    __syncthreads();
    m = redm[0];

    v0 = expf(v0 - m); v1 = expf(v1 - m); v2 = expf(v2 - m); v3 = expf(v3 - m);
    float s = v0 + v1 + v2 + v3;
    for (int o = 32; o > 0; o >>= 1) s += __shfl_down(s, o);
    if (lane == 0) reds[wid] = s;
    __syncthreads();
    if (t == 0) reds[0] = reds[0] + reds[1] + reds[2] + reds[3];
    __syncthreads();
    float inv = 1.f / reds[0];
    ushort4 o4;
    o4.x = tobf(v0 * inv); o4.y = tobf(v1 * inv);
    o4.z = tobf(v2 * inv); o4.w = tobf(v3 * inv);
    ((ushort4*)r)[t] = o4;
}

// ---------------------------------------------------------------------------
// 6) single-plane u16 transpose of fdd flat view [512][1024] -> fddT [1024][512]
// ---------------------------------------------------------------------------
__global__ void k_tposeU1(const u16* __restrict__ src, u16* __restrict__ dst) {
    __shared__ u16 tile[32][33];
    int b = blockIdx.z;
    const u16* sb = src + (size_t)b * (C_ * HW_);
    u16* db = dst + (size_t)b * (C_ * HW_);
    int c0 = blockIdx.x * 32, r0 = blockIdx.y * 32;
    int tx = threadIdx.x, ty = threadIdx.y;
    #pragma unroll
    for (int j = 0; j < 32; j += 8)
        tile[ty + j][tx] = sb[(size_t)(r0 + ty + j) * HW_ + c0 + tx];
    __syncthreads();
    #pragma unroll
    for (int j = 0; j < 32; j += 8)
        db[(size_t)(c0 + ty + j) * C_ + r0 + tx] = tile[tx][ty + j];
}

// ---------------------------------------------------------------------------
// 7) top-48, one WAVE per row (verified r8)
// ---------------------------------------------------------------------------
__device__ __forceinline__ float sort64_desc(float v, int lane) {
    #pragma unroll
    for (int k = 2; k <= 64; k <<= 1) {
        #pragma unroll
        for (int j = k >> 1; j > 0; j >>= 1) {
            float o = __shfl_xor(v, j);
            bool takeMax = (((lane & k) == 0) == ((lane & j) == 0));
            v = takeMax ? fmaxf(v, o) : fminf(v, o);
        }
    }
    return v;
}
__device__ __forceinline__ float bmerge64_desc(float a, float b, int lane) {
    float br = __shfl(b, 63 - lane);
    float c = fmaxf(a, br);
    #pragma unroll
    for (int j = 32; j > 0; j >>= 1) {
        float o = __shfl_xor(c, j);
        c = ((lane & j) == 0) ? fmaxf(c, o) : fminf(c, o);
    }
    return c;
}

__global__ __launch_bounds__(256) void k_topk(const float* __restrict__ corr,
                                              float* __restrict__ topv) {
    __shared__ float buf[4][1024];
    int wave = threadIdx.x >> 6, lane = threadIdx.x & 63;
    int row = blockIdx.x * 4 + wave;
    const float4* rp = (const float4*)(corr + (size_t)row * HW_);

    float4 e[4];
    #pragma unroll
    for (int q = 0; q < 4; ++q) e[q] = rp[lane * 4 + q];

    float gm = -INFINITY;
    #pragma unroll
    for (int q = 0; q < 4; ++q)
        gm = fmaxf(gm, fmaxf(fmaxf(e[q].x, e[q].y), fmaxf(e[q].z, e[q].w)));
    float sorted = sort64_desc(gm, lane);
    float tau = __shfl(sorted, T_ - 1);

    int c = 0;
    #pragma unroll
    for (int q = 0; q < 4; ++q)
        c += (e[q].x >= tau) + (e[q].y >= tau) + (e[q].z >= tau) + (e[q].w >= tau);
    int sc = c;
    #pragma unroll
    for (int o = 1; o < 64; o <<= 1) {
        int t2 = __shfl_up(sc, o);
        if (lane >= o) sc += t2;
    }
    int off = sc - c;
    int cnt = __shfl(sc, 63);

    float* wb = buf[wave];
    #pragma unroll
    for (int q = 0; q < 4; ++q) {
        if (e[q].x >= tau) wb[off++] = e[q].x;
        if (e[q].y >= tau) wb[off++] = e[q].y;
        if (e[q].z >= tau) wb[off++] = e[q].z;
        if (e[q].w >= tau) wb[off++] = e[q].w;
    }

    float* orow = topv + (size_t)row * T_;
    if (cnt <= 64) {
        float a = (lane < cnt) ? wb[lane] : -INFINITY;
        a = sort64_desc(a, lane);
        if (lane < T_) orow[lane] = fmaxf(a, 0.f);
    } else if (cnt <= 128) {
        float a  = sort64_desc(wb[lane], lane);
        float b2 = sort64_desc((lane < cnt - 64) ? wb[64 + lane] : -INFINITY, lane);
        float m2 = bmerge64_desc(a, b2, lane);
        if (lane < T_) orow[lane] = fmaxf(m2, 0.f);
    } else {
        int P = 256; while (P < cnt) P <<= 1;
        for (int i = cnt + lane; i < P; i += 64) wb[i] = -INFINITY;
        for (int k = 2; k <= P; k <<= 1)
            for (int j = k >> 1; j > 0; j >>= 1)
                for (int t2 = lane; t2 < P; t2 += 64) {
                    int ixj = t2 ^ j;
                    if (ixj > t2) {
                        float a = wb[t2], b3 = wb[ixj];
                        bool desc = ((t2 & k) == 0);
                        if (desc ? (a < b3) : (a > b3)) { wb[t2] = b3; wb[ixj] = a; }
                    }
                }
        if (lane < T_) orow[lane] = fmaxf(wb[lane], 0.f);
    }
}

// ---------------------------------------------------------------------------
// 8) column norm over (B,H) and final transpose
// ---------------------------------------------------------------------------
__global__ void k_colss(const float* __restrict__ topv, float* __restrict__ colss) {
    int o = blockIdx.x;
    int w = o / T_, t = o % T_;
    int lane = threadIdx.x;
    float s = 0.f;
    for (int i = lane; i < 512; i += 64) {
        int b = i >> 5, h = i & 31;
        float v = topv[(size_t)((b << 10) + (h << 5) + w) * T_ + t];
        s += v * v;
    }
    for (int off = 32; off > 0; off >>= 1) s += __shfl_down(s, off);
    if (lane == 0) colss[o] = s;
}

__global__ void k_final(const float* __restrict__ topv, const float* __restrict__ colss,
                        float* __restrict__ out) {
    int idx = blockIdx.x * 256 + threadIdx.x;
    if (idx >= B_ * T_ * HW_) return;
    int w = idx & 31;
    int h = (idx >> 5) & 31;
    int t = (idx >> 10) % T_;
    int b = idx / (T_ * HW_);
    float v = topv[(size_t)((b << 10) + (h << 5) + w) * T_ + t];
    out[idx] = v * rsqrtf(colss[w * T_ + t]);
}

// ---------------------------------------------------------------------------
extern "C" void kernel_launch(void* const* d_in, const int* in_sizes, int n_in,
                              void* d_out, int out_size, void* d_ws, size_t ws_size,
                              hipStream_t stream) {
    const float* x     = (const float*)d_in[0];
    const float* fW    = (const float*)d_in[1];
    const float* fb    = (const float*)d_in[2];
    const float* gW    = (const float*)d_in[3];
    const float* gb    = (const float*)d_in[4];
    const float* hW    = (const float*)d_in[5];
    const float* hb    = (const float*)d_in[6];
    const float* scale = (const float*)d_in[7];
    float* out = (float*)d_out;

    char* wsb = (char*)d_ws;
    float* part = (float*)(wsb + 0);                 // 131072 B
    float* ninv = (float*)(wsb + 131072);            // 4096 B
    u16*   hWh  = (u16*)(wsb + 135168);              // 524288 B
    u16*   fgWh = (u16*)(wsb + 1183744);             // 131072 B
    float* fgb  = (float*)(wsb + 1445888);           // 512 B
    u16*   xnH  = (u16*)(wsb + 1446400);             // 16 MB (xn bf16 -> fdd bf16)
    u16*   fgH  = (u16*)(wsb + 35000832);            // 4 MB (f|g bf16; later topv)
    u16*   fgL  = (u16*)(wsb + 39195136);            // 4 MB (later colss)
    u16*   hvTH = (u16*)(wsb + 43389440);            // 16 MB (hv bf16 -> fddT)
    float* S    = (float*)(wsb + 76943872);          // 64 MB (S/P u16 -> corr fp32)
    float* topv = (float*)fgH;
    float* colss= (float*)fgL;
    u16*   Sp   = (u16*)S;

    const long sXn = 524288;    // [1024][512] elements per batch
    const long sFG = 131072;    // [1024][128]
    const long sS  = 1048576;   // [1024][1024]

    // 1) per-pixel Frobenius norm
    k_colsq<<<128, 256, 0, stream>>>(x, part);
    k_rsqrt<<<4, 256, 0, stream>>>(part, ninv);

    // 2) normalized channel-last bf16 (single plane)
    k_transpose<<<dim3(32, 16, 16), dim3(32, 8), 0, stream>>>(x, ninv, xnH);

    // 3) weight planes
    k_packW<<<1024, 256, 0, stream>>>(hW, hWh);
    k_packFG<<<256, 256, 0, stream>>>(fW, gW, fb, gb, fgWh, fgb);

    // 4) fg = bf16(xn @ [fW|gW]^T + bias[col])  [B,1024,128]
    k_gemm1<0, 6><<<dim3(1, 8, 16), 256, 0, stream>>>(
        xnH, fgWh, fgb, nullptr, fgH, nullptr,
        128, 512, 512, 512, sXn, 0, sFG);

    // 5) hv = bf16(hW @ xn^T + hb[row])  [B,512,1024]
    k_gemm2<0, 5><<<dim3(4, 4, 16), 512, 0, stream>>>(
        hWh, xnH, hb, nullptr, hvTH, nullptr,
        1024, 512, 512, 512, 0, sXn, sXn);

    // 6) S = bf16(f @ perm(g)^T)  (K=64, W-major keys)
    k_gemm2<1, 4><<<dim3(4, 8, 16), 512, 0, stream>>>(
        fgH, fgH + 64, nullptr, nullptr, Sp, nullptr,
        1024, 64, 128, 128, sFG, sFG, sS);

    // 7) softmax rows, u16 in place -> P bf16
    k_softmax<<<B_ * HW_, 256, 0, stream>>>(Sp);

    // 8) fdd = bf16(scale*(P @ hv^T) + xn), in place over xnH (128x256 tile)
    k_gemm2<0, 2><<<dim3(2, 8, 16), 512, 0, stream>>>(
        Sp, hvTH, nullptr, nullptr, xnH, scale,
        512, 1024, 1024, 1024, sS, sXn, sXn);

    // 9) fddT: transpose flat [512][1024] view of fddH -> hvTH [1024][512]
    k_tposeU1<<<dim3(32, 16, 16), dim3(32, 8), 0, stream>>>(xnH, hvTH);

    // 10) corr = fdd @ fddT^T -> fp32 into S
    k_gemm2<0, 0><<<dim3(4, 8, 16), 512, 0, stream>>>(
        xnH, hvTH, nullptr, S, nullptr, nullptr,
        1024, 512, 512, 512, sXn, sXn, sS);

    // 11) top-48 desc + relu (wave-per-row)
    k_topk<<<B_ * HW_ / 4, 256, 0, stream>>>(S, topv);

    // 12) norm over (B,H) + output transpose
    k_colss<<<W_ * T_, 64, 0, stream>>>(topv, colss);
    k_final<<<(B_ * T_ * HW_ + 255) / 256, 256, 0, stream>>>(topv, colss, out);
}